// Round 9
// baseline (46.637 us; speedup 1.0000x reference)
//
#include <hip/hip_runtime.h>
#include <cmath>

#define NMAX    8
#define NM      25
#define ROWW    40     // slab row: 10 float4s: [0..7]=g, [8..39]=permuted Y + zeros
#define SLABR   14     // slab rows per wave
#define NOUT    1080
#define CROW    36     // c row: l-blocks packed 4+4+8+8+12, pads zeroed
#define CSLICE  288    // 8 * 36

struct Params {
    float W[NMAX * NMAX];
    float invnorm[NMAX];
    float ycoef[NM];        // sph-harm coefficients * 4*pi
    float lscale[5];
    float pairf[6];
};

// heavy per-neighbor compute: writes g[8] + permuted Y into row (10 x b128)
__device__ __forceinline__ void neighbor_compute(const Params& prm,
                                                 float dx, float dy, float dz,
                                                 float* __restrict__ row) {
    const float d2 = dx * dx + dy * dy + dz * dz;
    const float dist = sqrtf(d2);
    const float inv  = dist > 0.f ? 1.f / dist : 0.f;
    const float x = dx * inv, y = dy * inv, z = dz * inv;
    const float x2 = x * x, y2 = y * y, z2 = z * z;
    const float r2 = x2 + y2 + z2;

    const float dr = 5.f - dist;
    float bas[NMAX];
    float drp = dr * dr * dr;
#pragma unroll
    for (int a = 0; a < NMAX; ++a) { bas[a] = drp * prm.invnorm[a]; drp *= dr; }
    float g[NMAX];
#pragma unroll
    for (int n = 0; n < NMAX; ++n) {
        float acc = 0.f;
#pragma unroll
        for (int a = 0; a < NMAX; ++a) acc += bas[a] * prm.W[n * NMAX + a];
        g[n] = acc;
    }

    float Yv[NM];
    Yv[0]  = prm.ycoef[0];
    Yv[1]  = prm.ycoef[1]  * y;
    Yv[2]  = prm.ycoef[2]  * z;
    Yv[3]  = prm.ycoef[3]  * x;
    Yv[4]  = prm.ycoef[4]  * x * y;
    Yv[5]  = prm.ycoef[5]  * y * z;
    Yv[6]  = prm.ycoef[6]  * (3.f * z2 - r2);
    Yv[7]  = prm.ycoef[7]  * x * z;
    Yv[8]  = prm.ycoef[8]  * (x2 - y2);
    Yv[9]  = prm.ycoef[9]  * y * (3.f * x2 - y2);
    Yv[10] = prm.ycoef[10] * x * y * z;
    Yv[11] = prm.ycoef[11] * y * (5.f * z2 - r2);
    Yv[12] = prm.ycoef[12] * z * (5.f * z2 - 3.f * r2);
    Yv[13] = prm.ycoef[13] * x * (5.f * z2 - r2);
    Yv[14] = prm.ycoef[14] * z * (x2 - y2);
    Yv[15] = prm.ycoef[15] * x * (x2 - 3.f * y2);
    Yv[16] = prm.ycoef[16] * x * y * (x2 - y2);
    Yv[17] = prm.ycoef[17] * y * z * (3.f * x2 - y2);
    Yv[18] = prm.ycoef[18] * x * y * (7.f * z2 - r2);
    Yv[19] = prm.ycoef[19] * y * z * (7.f * z2 - 3.f * r2);
    Yv[20] = prm.ycoef[20] * (35.f * z2 * z2 - 30.f * z2 * r2 + 3.f * r2 * r2);
    Yv[21] = prm.ycoef[21] * x * z * (7.f * z2 - 3.f * r2);
    Yv[22] = prm.ycoef[22] * (x2 - y2) * (7.f * z2 - r2);
    Yv[23] = prm.ycoef[23] * x * z * (x2 - 3.f * y2);
    Yv[24] = prm.ycoef[24] * (x2 * x2 - 6.f * x2 * y2 + y2 * y2);

    // permuted: quad[2+mrow] = {Y[mrow], Y[mrow+8], Y[mrow+16], Y[mrow+24]|0}
    float4* q = (float4*)row;
    q[0] = make_float4(g[0], g[1], g[2], g[3]);
    q[1] = make_float4(g[4], g[5], g[6], g[7]);
    q[2] = make_float4(Yv[0], Yv[8],  Yv[16], Yv[24]);
    q[3] = make_float4(Yv[1], Yv[9],  Yv[17], 0.f);
    q[4] = make_float4(Yv[2], Yv[10], Yv[18], 0.f);
    q[5] = make_float4(Yv[3], Yv[11], Yv[19], 0.f);
    q[6] = make_float4(Yv[4], Yv[12], Yv[20], 0.f);
    q[7] = make_float4(Yv[5], Yv[13], Yv[21], 0.f);
    q[8] = make_float4(Yv[6], Yv[14], Yv[22], 0.f);
    q[9] = make_float4(Yv[7], Yv[15], Yv[23], 0.f);
}

__global__ __launch_bounds__(256)
void soap_kernel(const float* __restrict__ pos, const int* __restrict__ Z,
                 float* __restrict__ out, Params prm) {
    // one site per block; 4 waves each own 128 candidates (NO duplicated work);
    // per-wave partial c merged via LDS float atomics; 2 barriers total.
    __shared__ float4 dA[4][64];                       // per-wave, per-chunk compacted
    __shared__ __align__(16) float slab[4][SLABR * ROWW];
    __shared__ __align__(16) float c2[3 * CSLICE];     // [s][n][36]

    const int tid  = threadIdx.x;
    const int lane = tid & 63;
    const int w    = tid >> 6;
    const int site = blockIdx.x;
    const int jbase = (site >> 9) << 9;
    const unsigned long long ltm = (1ull << lane) - 1ull;

    const float xi = pos[site * 3 + 0];
    const float yi = pos[site * 3 + 1];
    const float zi = pos[site * 3 + 2];

    // zero c2 (216 float4s) cooperatively
    {
        float4* c4 = (float4*)c2;
        if (tid < 216) c4[tid] = make_float4(0.f, 0.f, 0.f, 0.f);
    }
    __syncthreads();   // barrier #1: zeroing complete before any atomic add

    const int n_own = lane & 7;
    const int mrow  = lane >> 3;
    float a0[4] = {0.f,0.f,0.f,0.f};
    float a1[4] = {0.f,0.f,0.f,0.f};
    float a2[4] = {0.f,0.f,0.f,0.f};
    const float* yb = &slab[w][8 + 4 * mrow];

    // ---- each wave: 2 chunks of 64 candidates; compact->compute->accumulate ----
    for (int cc = 0; cc < 2; ++cc) {
        const int ja = jbase + (2 * w + cc) * 64 + lane;
        const float dx = xi - pos[ja * 3 + 0];
        const float dy = yi - pos[ja * 3 + 1];
        const float dz = zi - pos[ja * 3 + 2];
        const float d2 = dx * dx + dy * dy + dz * dz;
        const int zz = Z[ja];
        const int sp = (zz == 1) ? 0 : (zz == 6) ? 1 : 2;
        const bool pr = d2 < 25.0f;
        const unsigned long long b0 = __ballot(pr && sp == 0);
        const unsigned long long b1 = __ballot(pr && sp == 1);
        const unsigned long long b2 = __ballot(pr && sp == 2);
        const int R1  = __popcll(b0);
        const int R2  = R1 + __popcll(b1);
        const int cnt = R2 + __popcll(b2);
        if (pr) {
            const int ppos = (sp == 0) ? __popcll(b0 & ltm)
                           : (sp == 1) ? R1 + __popcll(b1 & ltm)
                                       : R2 + __popcll(b2 & ltm);
            dA[w][ppos] = make_float4(dx, dy, dz, 0.f);   // in-wave DS ordering
        }
        for (int rb = 0; rb < cnt; rb += SLABR) {
            const int k = min(SLABR, cnt - rb);
            if (lane < k) {
                const float4 u = dA[w][rb + lane];
                neighbor_compute(prm, u.x, u.y, u.z, &slab[w][lane * ROWW]);
            }
            for (int sl = 0; sl < k; ++sl) {
                const float g  = slab[w][sl * ROWW + n_own];
                const float4 y4 = *(const float4*)&yb[sl * ROWW];
                const int gsl = rb + sl;
                if (gsl < R1) {          // wave-uniform branch
                    a0[0] += g * y4.x; a0[1] += g * y4.y; a0[2] += g * y4.z; a0[3] += g * y4.w;
                } else if (gsl < R2) {
                    a1[0] += g * y4.x; a1[1] += g * y4.y; a1[2] += g * y4.z; a1[3] += g * y4.w;
                } else {
                    a2[0] += g * y4.x; a2[1] += g * y4.y; a2[2] += g * y4.z; a2[3] += g * y4.w;
                }
            }
        }
    }

    // ---- merge partial c via LDS float atomics (12 adds/lane, masked) ----
#pragma unroll
    for (int k = 0; k < 4; ++k) {
        const int m = mrow + 8 * k;
        if (k < 3 || mrow == 0) {       // m < 25
            const int l  = (int)sqrtf((float)m);   // exact at perfect squares
            const int kk = m - l * l;
            const int lofs = (l < 2) ? 4 * l : 8 * (l - 1);
            const int idx = n_own * CROW + lofs + kk;
            atomicAdd(&c2[idx             ], a0[k]);
            atomicAdd(&c2[idx +     CSLICE], a1[k]);
            atomicAdd(&c2[idx + 2 * CSLICE], a2[k]);
        }
    }
    __syncthreads();   // barrier #2: c complete

    // ---- C: 1080 outputs over 256 threads; conflict-free b128, coalesced stores ----
#pragma unroll
    for (int it = 0; it < 5; ++it) {
        const int o = it * 256 + tid;
        if (o < NOUT) {
            const int q   = o / 180;
            const int rem = o - q * 180;
            const int l   = rem / 36;
            const int t   = rem - l * 36;
            const int n = (int)((17.0f - sqrtf((float)(289 - 8 * t))) * 0.5f);
            const int p = t - ((n * (17 - n)) >> 1) + n;
            const int s1 = (q < 3) ? 0 : ((q < 5) ? 1 : 2);
            const int s2 = (q < 3) ? q : ((q < 5) ? (q - 2) : 2);
            const int lofs = (l < 2) ? 4 * l : 8 * (l - 1);
            const int nq   = (l < 2) ? 1 : ((l < 4) ? 2 : 3);
            const float4* ra = (const float4*)&c2[s1 * CSLICE + n * CROW + lofs];
            const float4* rb = (const float4*)&c2[s2 * CSLICE + p * CROW + lofs];
            float sum = 0.f;
            for (int j = 0; j < nq; ++j) {
                const float4 av = ra[j], bv = rb[j];
                sum += av.x * bv.x + av.y * bv.y + av.z * bv.z + av.w * bv.w;
            }
            float sc = prm.pairf[q] * prm.lscale[l];
            if (n != p) sc *= 1.41421356237309515f;
            out[site * NOUT + o] = sum * sc;
        }
    }
}

extern "C" void kernel_launch(void* const* d_in, const int* in_sizes, int n_in,
                              void* d_out, int out_size, void* d_ws, size_t ws_size,
                              hipStream_t stream) {
    const float* pos = (const float*)d_in[0];
    const int*   Z   = (const int*)d_in[1];
    float*       out = (float*)d_out;
    const int nsite  = in_sizes[1];   // B*N = 2048

    Params prm;

    // ---- W_ORTHO = S^(-1/2) via cyclic Jacobi (double precision, host) ----
    double A[8][8], V[8][8];
    for (int i = 0; i < 8; ++i)
        for (int j = 0; j < 8; ++j) {
            const double ai = i + 1.0, aj = j + 1.0;
            A[i][j] = sqrt((5.0 + 2.0 * ai) * (5.0 + 2.0 * aj)) / (5.0 + ai + aj);
            V[i][j] = (i == j) ? 1.0 : 0.0;
        }
    for (int sweep = 0; sweep < 30; ++sweep) {
        for (int p = 0; p < 8; ++p)
            for (int q = p + 1; q < 8; ++q) {
                const double apq = A[p][q];
                if (fabs(apq) < 1e-300) continue;
                const double phi = 0.5 * atan2(2.0 * apq, A[q][q] - A[p][p]);
                const double c = cos(phi), s = sin(phi);
                for (int k = 0; k < 8; ++k) {
                    const double akp = A[k][p], akq = A[k][q];
                    A[k][p] = c * akp - s * akq;
                    A[k][q] = s * akp + c * akq;
                }
                for (int k = 0; k < 8; ++k) {
                    const double apk = A[p][k], aqk = A[q][k];
                    A[p][k] = c * apk - s * aqk;
                    A[q][k] = s * apk + c * aqk;
                }
                for (int k = 0; k < 8; ++k) {
                    const double vkp = V[k][p], vkq = V[k][q];
                    V[k][p] = c * vkp - s * vkq;
                    V[k][q] = s * vkp + c * vkq;
                }
            }
    }
    for (int i = 0; i < 8; ++i)
        for (int j = 0; j < 8; ++j) {
            double acc = 0.0;
            for (int k = 0; k < 8; ++k) acc += V[i][k] * V[j][k] / sqrt(A[k][k]);
            prm.W[i * 8 + j] = (float)acc;
        }

    for (int a = 0; a < 8; ++a)
        prm.invnorm[a] = (float)(1.0 / sqrt(pow(5.0, 2.0 * a + 7.0) / (2.0 * a + 7.0)));

    const double pi = 3.14159265358979323846;
    const double fp = 4.0 * pi;
    double yc[NM];
    yc[0]  = 0.5 * sqrt(1.0 / pi);
    yc[1]  = yc[2] = yc[3] = sqrt(3.0 / (4.0 * pi));
    yc[4]  = yc[5] = yc[7] = 0.5 * sqrt(15.0 / pi);
    yc[6]  = 0.25 * sqrt(5.0 / pi);
    yc[8]  = 0.25 * sqrt(15.0 / pi);
    yc[9]  = yc[15] = 0.25 * sqrt(35.0 / (2.0 * pi));
    yc[10] = 0.5 * sqrt(105.0 / pi);
    yc[11] = yc[13] = 0.25 * sqrt(21.0 / (2.0 * pi));
    yc[12] = 0.25 * sqrt(7.0 / pi);
    yc[14] = 0.25 * sqrt(105.0 / pi);
    yc[16] = 0.75 * sqrt(35.0 / pi);
    yc[17] = yc[23] = 0.75 * sqrt(35.0 / (2.0 * pi));
    yc[18] = 0.75 * sqrt(5.0 / pi);
    yc[19] = yc[21] = 0.75 * sqrt(5.0 / (2.0 * pi));
    yc[20] = 3.0 / 16.0 * sqrt(1.0 / pi);
    yc[22] = 3.0 / 8.0 * sqrt(5.0 / pi);
    yc[24] = 3.0 / 16.0 * sqrt(35.0 / pi);
    for (int m = 0; m < NM; ++m) prm.ycoef[m] = (float)(yc[m] * fp);

    for (int l = 0; l <= 4; ++l) prm.lscale[l] = (float)(pi * sqrt(8.0 / (2.0 * l + 1.0)));
    const float rt2 = 1.41421356237309515f;
    prm.pairf[0] = 1.f; prm.pairf[1] = rt2; prm.pairf[2] = rt2;
    prm.pairf[3] = 1.f; prm.pairf[4] = rt2; prm.pairf[5] = 1.f;

    soap_kernel<<<nsite, 256, 0, stream>>>(pos, Z, out, prm);
}

// Round 10
// 22.118 us; speedup vs baseline: 2.1085x; 2.1085x over previous
//
#include <hip/hip_runtime.h>
#include <cmath>

#define NMAX    8
#define NM      25
#define ROWW    44     // slab row stride (floats); 12 mod 32 -> bank spread
#define SEGC    20     // per (wave,chunk) segment capacity (~3 hits typical)
#define NOUT    1080
#define CROW    36     // c row: l-blocks packed 4+4+8+8+12, pads zeroed
#define CSLICE  288    // 8 * 36

struct Params {
    float W[NMAX * NMAX];
    float invnorm[NMAX];
    float ycoef[NM];        // sph-harm coefficients * 4*pi
    float lscale[5];
    float pairf[6];
};

struct COut { unsigned int meta; float scale; };   // meta = offA | offB<<12 | nq<<24

// heavy per-neighbor compute: writes g[8] + permuted Y into row (10 x b128)
__device__ __forceinline__ void neighbor_compute(const Params& prm,
                                                 float dx, float dy, float dz,
                                                 float* __restrict__ row) {
    const float d2 = dx * dx + dy * dy + dz * dz;
    const float dist = sqrtf(d2);
    const float inv  = dist > 0.f ? 1.f / dist : 0.f;
    const float x = dx * inv, y = dy * inv, z = dz * inv;
    const float x2 = x * x, y2 = y * y, z2 = z * z;
    const float r2 = x2 + y2 + z2;

    const float dr = 5.f - dist;
    float bas[NMAX];
    float drp = dr * dr * dr;
#pragma unroll
    for (int a = 0; a < NMAX; ++a) { bas[a] = drp * prm.invnorm[a]; drp *= dr; }
    float g[NMAX];
#pragma unroll
    for (int n = 0; n < NMAX; ++n) {
        float acc = 0.f;
#pragma unroll
        for (int a = 0; a < NMAX; ++a) acc += bas[a] * prm.W[n * NMAX + a];
        g[n] = acc;
    }

    float Yv[NM];
    Yv[0]  = prm.ycoef[0];
    Yv[1]  = prm.ycoef[1]  * y;
    Yv[2]  = prm.ycoef[2]  * z;
    Yv[3]  = prm.ycoef[3]  * x;
    Yv[4]  = prm.ycoef[4]  * x * y;
    Yv[5]  = prm.ycoef[5]  * y * z;
    Yv[6]  = prm.ycoef[6]  * (3.f * z2 - r2);
    Yv[7]  = prm.ycoef[7]  * x * z;
    Yv[8]  = prm.ycoef[8]  * (x2 - y2);
    Yv[9]  = prm.ycoef[9]  * y * (3.f * x2 - y2);
    Yv[10] = prm.ycoef[10] * x * y * z;
    Yv[11] = prm.ycoef[11] * y * (5.f * z2 - r2);
    Yv[12] = prm.ycoef[12] * z * (5.f * z2 - 3.f * r2);
    Yv[13] = prm.ycoef[13] * x * (5.f * z2 - r2);
    Yv[14] = prm.ycoef[14] * z * (x2 - y2);
    Yv[15] = prm.ycoef[15] * x * (x2 - 3.f * y2);
    Yv[16] = prm.ycoef[16] * x * y * (x2 - y2);
    Yv[17] = prm.ycoef[17] * y * z * (3.f * x2 - y2);
    Yv[18] = prm.ycoef[18] * x * y * (7.f * z2 - r2);
    Yv[19] = prm.ycoef[19] * y * z * (7.f * z2 - 3.f * r2);
    Yv[20] = prm.ycoef[20] * (35.f * z2 * z2 - 30.f * z2 * r2 + 3.f * r2 * r2);
    Yv[21] = prm.ycoef[21] * x * z * (7.f * z2 - 3.f * r2);
    Yv[22] = prm.ycoef[22] * (x2 - y2) * (7.f * z2 - r2);
    Yv[23] = prm.ycoef[23] * x * z * (x2 - 3.f * y2);
    Yv[24] = prm.ycoef[24] * (x2 * x2 - 6.f * x2 * y2 + y2 * y2);

    // permuted: quad[2+k] = {Y[k], Y[k+8], Y[k+16], Y[k+24]|0}; Y[m] at 8+4*(m&7)+(m>>3)
    float4* q = (float4*)row;
    q[0] = make_float4(g[0], g[1], g[2], g[3]);
    q[1] = make_float4(g[4], g[5], g[6], g[7]);
    q[2] = make_float4(Yv[0], Yv[8],  Yv[16], Yv[24]);
    q[3] = make_float4(Yv[1], Yv[9],  Yv[17], 0.f);
    q[4] = make_float4(Yv[2], Yv[10], Yv[18], 0.f);
    q[5] = make_float4(Yv[3], Yv[11], Yv[19], 0.f);
    q[6] = make_float4(Yv[4], Yv[12], Yv[20], 0.f);
    q[7] = make_float4(Yv[5], Yv[13], Yv[21], 0.f);
    q[8] = make_float4(Yv[6], Yv[14], Yv[22], 0.f);
    q[9] = make_float4(Yv[7], Yv[15], Yv[23], 0.f);
}

template<int USE_TAB>
__global__ __launch_bounds__(256, 8)
void soap_kernel(const float* __restrict__ pos, const int* __restrict__ Z,
                 const COut* __restrict__ ctab, float* __restrict__ out, Params prm) {
    // one site per 256-thread block; 4 waves, zero duplicated work, 3 barriers
    __shared__ float4 dA[8][SEGC];                 // per (wave,chunk) compacted hits
    __shared__ __align__(16) int scnt[8];          // per-segment counts
    __shared__ float spf[64];                      // species per merged slot
    __shared__ __align__(16) float slab[64 * ROWW];
    __shared__ __align__(16) float c2[3 * CSLICE];

    const int tid  = threadIdx.x;
    const int lane = tid & 63;
    const int w    = tid >> 6;
    const int site = blockIdx.x;
    const int jbase = (site >> 9) << 9;
    const unsigned long long ltm = (1ull << lane) - 1ull;

    const float xi = pos[site * 3 + 0];
    const float yi = pos[site * 3 + 1];
    const float zi = pos[site * 3 + 2];

    // zero c2 (pads must read 0): 216 quads
    if (tid < 216) ((float4*)c2)[tid] = make_float4(0.f, 0.f, 0.f, 0.f);

    // ---- A1: wave w scans ONLY its 128 candidates (2 chunks), compacts ----
#pragma unroll
    for (int cc = 0; cc < 2; ++cc) {
        const int seg = 2 * w + cc;
        const int ja  = jbase + seg * 64 + lane;
        const float dx = xi - pos[ja * 3 + 0];
        const float dy = yi - pos[ja * 3 + 1];
        const float dz = zi - pos[ja * 3 + 2];
        const float d2 = dx * dx + dy * dy + dz * dz;
        const bool pr = d2 < 25.0f;
        const unsigned long long mk = __ballot(pr);
        if (pr) {
            const int ppos = __popcll(mk & ltm);
            if (ppos < SEGC) {
                const int zz = Z[ja];
                const float sp = (zz == 1) ? 0.f : (zz == 6) ? 1.f : 2.f;
                dA[seg][ppos] = make_float4(dx, dy, dz, sp);
            }
        }
        if (lane == 0) scnt[seg] = min(__popcll(mk), SEGC);
    }
    __syncthreads();   // barrier 1: segments + counts visible

    // ---- prefix over 8 segment counts (2 b128 broadcast reads) ----
    const int4 cA = *(const int4*)&scnt[0];
    const int4 cB = *(const int4*)&scnt[4];
    const int p1 = cA.x,      p2 = p1 + cA.y, p3 = p2 + cA.z, p4 = p3 + cA.w;
    const int p5 = p4 + cB.x, p6 = p5 + cB.y, p7 = p6 + cB.z, p8 = p7 + cB.w;
    const int M  = min(p8, 64);

    // ---- gather + heavy: wave w owns merged slots [16w, 16w+16) ----
    if (lane < 16) {
        const int g = 16 * w + lane;
        if (g < M) {
            const int seg = (g >= p1) + (g >= p2) + (g >= p3) + (g >= p4)
                          + (g >= p5) + (g >= p6) + (g >= p7);
            int base = 0;
            base = (g >= p1) ? p1 : base;
            base = (g >= p2) ? p2 : base;
            base = (g >= p3) ? p3 : base;
            base = (g >= p4) ? p4 : base;
            base = (g >= p5) ? p5 : base;
            base = (g >= p6) ? p6 : base;
            base = (g >= p7) ? p7 : base;
            const float4 u = dA[seg][g - base];
            spf[g] = u.w;
            neighbor_compute(prm, u.x, u.y, u.z, &slab[g * ROWW]);
        }
    }
    __syncthreads();   // barrier 2: slab + spf complete

    // ---- B: thread owns (n_own, mown = 4*mrow + w); no atomics ----
    {
        const int n_own = lane & 7;
        const int mrow  = lane >> 3;
        const int mown  = 4 * mrow + w;
        const int yoff  = 8 + 4 * (mown & 7) + (mown >> 3);
        float a0 = 0.f, a1 = 0.f, a2 = 0.f;
        for (int sl = 0; sl < M; ++sl) {
            const float g  = slab[sl * ROWW + n_own];   // broadcast x8
            const float y  = slab[sl * ROWW + yoff];    // broadcast x8, distinct banks
            const float sp = spf[sl];                   // broadcast x64
            if (sp == 0.f)      a0 += g * y;            // wave-uniform branch
            else if (sp == 1.f) a1 += g * y;
            else                a2 += g * y;
        }
        if (mown < NM) {
            const int l  = (int)sqrtf((float)mown);     // exact at perfect squares
            const int kk = mown - l * l;
            const int lofs = (l < 2) ? 4 * l : 8 * (l - 1);
            const int idx  = n_own * CROW + lofs + kk;
            c2[idx             ] = a0;
            c2[idx +     CSLICE] = a1;
            c2[idx + 2 * CSLICE] = a2;
        }
    }
    __syncthreads();   // barrier 3: c2 complete

    // ---- C: 1080 outputs over 256 threads ----
#pragma unroll
    for (int it = 0; it < 5; ++it) {
        const int o = it * 256 + tid;
        if (o < NOUT) {
            int offA, offB, nq;
            float sc;
            if (USE_TAB) {
                const COut e = ctab[o];
                offA = e.meta & 0xFFF;
                offB = (e.meta >> 12) & 0xFFF;
                nq   = e.meta >> 24;
                sc   = e.scale;
            } else {
                const int q   = o / 180;
                const int rem = o - q * 180;
                const int l   = rem / 36;
                const int t   = rem - l * 36;
                const int n = (int)((17.0f - sqrtf((float)(289 - 8 * t))) * 0.5f);
                const int p = t - ((n * (17 - n)) >> 1) + n;
                const int s1 = (q < 3) ? 0 : ((q < 5) ? 1 : 2);
                const int s2 = (q < 3) ? q : ((q < 5) ? (q - 2) : 2);
                const int lofs = (l < 2) ? 4 * l : 8 * (l - 1);
                nq   = (l < 2) ? 1 : ((l < 4) ? 2 : 3);
                offA = s1 * CSLICE + n * CROW + lofs;
                offB = s2 * CSLICE + p * CROW + lofs;
                sc = prm.pairf[q] * prm.lscale[l];
                if (n != p) sc *= 1.41421356237309515f;
            }
            const float4* ra = (const float4*)&c2[offA];
            const float4* rb = (const float4*)&c2[offB];
            float sum = 0.f;
            for (int j = 0; j < nq; ++j) {
                const float4 av = ra[j], bv = rb[j];
                sum += av.x * bv.x + av.y * bv.y + av.z * bv.z + av.w * bv.w;
            }
            out[site * NOUT + o] = sum * sc;
        }
    }
}

extern "C" void kernel_launch(void* const* d_in, const int* in_sizes, int n_in,
                              void* d_out, int out_size, void* d_ws, size_t ws_size,
                              hipStream_t stream) {
    const float* pos = (const float*)d_in[0];
    const int*   Z   = (const int*)d_in[1];
    float*       out = (float*)d_out;
    const int nsite  = in_sizes[1];   // B*N = 2048

    Params prm;

    // ---- W_ORTHO = S^(-1/2) via cyclic Jacobi (double precision, host) ----
    double A[8][8], V[8][8];
    for (int i = 0; i < 8; ++i)
        for (int j = 0; j < 8; ++j) {
            const double ai = i + 1.0, aj = j + 1.0;
            A[i][j] = sqrt((5.0 + 2.0 * ai) * (5.0 + 2.0 * aj)) / (5.0 + ai + aj);
            V[i][j] = (i == j) ? 1.0 : 0.0;
        }
    for (int sweep = 0; sweep < 30; ++sweep) {
        for (int p = 0; p < 8; ++p)
            for (int q = p + 1; q < 8; ++q) {
                const double apq = A[p][q];
                if (fabs(apq) < 1e-300) continue;
                const double phi = 0.5 * atan2(2.0 * apq, A[q][q] - A[p][p]);
                const double c = cos(phi), s = sin(phi);
                for (int k = 0; k < 8; ++k) {
                    const double akp = A[k][p], akq = A[k][q];
                    A[k][p] = c * akp - s * akq;
                    A[k][q] = s * akp + c * akq;
                }
                for (int k = 0; k < 8; ++k) {
                    const double apk = A[p][k], aqk = A[q][k];
                    A[p][k] = c * apk - s * aqk;
                    A[q][k] = s * apk + c * aqk;
                }
                for (int k = 0; k < 8; ++k) {
                    const double vkp = V[k][p], vkq = V[k][q];
                    V[k][p] = c * vkp - s * vkq;
                    V[k][q] = s * vkp + c * vkq;
                }
            }
    }
    for (int i = 0; i < 8; ++i)
        for (int j = 0; j < 8; ++j) {
            double acc = 0.0;
            for (int k = 0; k < 8; ++k) acc += V[i][k] * V[j][k] / sqrt(A[k][k]);
            prm.W[i * 8 + j] = (float)acc;
        }

    for (int a = 0; a < 8; ++a)
        prm.invnorm[a] = (float)(1.0 / sqrt(pow(5.0, 2.0 * a + 7.0) / (2.0 * a + 7.0)));

    const double pi = 3.14159265358979323846;
    const double fp = 4.0 * pi;
    double yc[NM];
    yc[0]  = 0.5 * sqrt(1.0 / pi);
    yc[1]  = yc[2] = yc[3] = sqrt(3.0 / (4.0 * pi));
    yc[4]  = yc[5] = yc[7] = 0.5 * sqrt(15.0 / pi);
    yc[6]  = 0.25 * sqrt(5.0 / pi);
    yc[8]  = 0.25 * sqrt(15.0 / pi);
    yc[9]  = yc[15] = 0.25 * sqrt(35.0 / (2.0 * pi));
    yc[10] = 0.5 * sqrt(105.0 / pi);
    yc[11] = yc[13] = 0.25 * sqrt(21.0 / (2.0 * pi));
    yc[12] = 0.25 * sqrt(7.0 / pi);
    yc[14] = 0.25 * sqrt(105.0 / pi);
    yc[16] = 0.75 * sqrt(35.0 / pi);
    yc[17] = yc[23] = 0.75 * sqrt(35.0 / (2.0 * pi));
    yc[18] = 0.75 * sqrt(5.0 / pi);
    yc[19] = yc[21] = 0.75 * sqrt(5.0 / (2.0 * pi));
    yc[20] = 3.0 / 16.0 * sqrt(1.0 / pi);
    yc[22] = 3.0 / 8.0 * sqrt(5.0 / pi);
    yc[24] = 3.0 / 16.0 * sqrt(35.0 / pi);
    for (int m = 0; m < NM; ++m) prm.ycoef[m] = (float)(yc[m] * fp);

    for (int l = 0; l <= 4; ++l) prm.lscale[l] = (float)(pi * sqrt(8.0 / (2.0 * l + 1.0)));
    const float rt2 = 1.41421356237309515f;
    prm.pairf[0] = 1.f; prm.pairf[1] = rt2; prm.pairf[2] = rt2;
    prm.pairf[3] = 1.f; prm.pairf[4] = rt2; prm.pairf[5] = 1.f;

    // ---- build C-phase decode table (deterministic each call) ----
    static COut tab[NOUT];
    {
        int TN[36], TP[36], ti = 0;
        for (int n = 0; n < 8; ++n)
            for (int p = n; p < 8; ++p) { TN[ti] = n; TP[ti] = p; ++ti; }
        const int PS1[6] = {0,0,0,1,1,2}, PS2[6] = {0,1,2,1,2,2};
        for (int o = 0; o < NOUT; ++o) {
            const int q = o / 180, rem = o % 180, l = rem / 36, t = rem % 36;
            const int n = TN[t], p = TP[t];
            const int lofs = (l < 2) ? 4 * l : 8 * (l - 1);
            const unsigned nq = (l < 2) ? 1u : ((l < 4) ? 2u : 3u);
            const unsigned offA = PS1[q] * CSLICE + n * CROW + lofs;
            const unsigned offB = PS2[q] * CSLICE + p * CROW + lofs;
            tab[o].meta  = offA | (offB << 12) | (nq << 24);
            double sc = (PS1[q] != PS2[q] ? sqrt(2.0) : 1.0)
                      * (pi * sqrt(8.0 / (2.0 * l + 1.0)))
                      * ((n != p) ? sqrt(2.0) : 1.0);
            tab[o].scale = (float)sc;
        }
    }

    if (ws_size >= sizeof(tab)) {
        hipMemcpyAsync(d_ws, tab, sizeof(tab), hipMemcpyHostToDevice, stream);
        soap_kernel<1><<<nsite, 256, 0, stream>>>(pos, Z, (const COut*)d_ws, out, prm);
    } else {
        soap_kernel<0><<<nsite, 256, 0, stream>>>(pos, Z, nullptr, out, prm);
    }
}

// Round 11
// 21.062 us; speedup vs baseline: 2.2142x; 1.0501x over previous
//
#include <hip/hip_runtime.h>
#include <cmath>

#define NMAX     8
#define NM       25
#define ROWW     40     // slab row: 10 float4: [0..7]=g, [8..39]=permuted Y (+pad)
#define SLABROWS 76     // 64 + bucket padding headroom
#define NOUT     1080
#define CROW     36     // c row: l-blocks packed 4+4+8+8+12, pads zeroed
#define CSLICE   288    // 8 * 36

struct Params {
    float W[NMAX * NMAX];
    float invnorm[NMAX];
    float ycoef[NM];        // sph-harm coefficients * 4*pi
    float lscale[5];
    float pairf[6];
};

// heavy per-neighbor compute: writes g[8] + permuted Y into row (10 x b128)
__device__ __forceinline__ void neighbor_compute(const Params& prm,
                                                 float dx, float dy, float dz,
                                                 float* __restrict__ row) {
    const float d2 = dx * dx + dy * dy + dz * dz;
    const float dist = sqrtf(d2);
    const float inv  = dist > 0.f ? 1.f / dist : 0.f;
    const float x = dx * inv, y = dy * inv, z = dz * inv;
    const float x2 = x * x, y2 = y * y, z2 = z * z;
    const float r2 = x2 + y2 + z2;

    const float dr = 5.f - dist;
    float bas[NMAX];
    float drp = dr * dr * dr;
#pragma unroll
    for (int a = 0; a < NMAX; ++a) { bas[a] = drp * prm.invnorm[a]; drp *= dr; }
    float g[NMAX];
#pragma unroll
    for (int n = 0; n < NMAX; ++n) {
        float acc = 0.f;
#pragma unroll
        for (int a = 0; a < NMAX; ++a) acc += bas[a] * prm.W[n * NMAX + a];
        g[n] = acc;
    }

    float Yv[NM];
    Yv[0]  = prm.ycoef[0];
    Yv[1]  = prm.ycoef[1]  * y;
    Yv[2]  = prm.ycoef[2]  * z;
    Yv[3]  = prm.ycoef[3]  * x;
    Yv[4]  = prm.ycoef[4]  * x * y;
    Yv[5]  = prm.ycoef[5]  * y * z;
    Yv[6]  = prm.ycoef[6]  * (3.f * z2 - r2);
    Yv[7]  = prm.ycoef[7]  * x * z;
    Yv[8]  = prm.ycoef[8]  * (x2 - y2);
    Yv[9]  = prm.ycoef[9]  * y * (3.f * x2 - y2);
    Yv[10] = prm.ycoef[10] * x * y * z;
    Yv[11] = prm.ycoef[11] * y * (5.f * z2 - r2);
    Yv[12] = prm.ycoef[12] * z * (5.f * z2 - 3.f * r2);
    Yv[13] = prm.ycoef[13] * x * (5.f * z2 - r2);
    Yv[14] = prm.ycoef[14] * z * (x2 - y2);
    Yv[15] = prm.ycoef[15] * x * (x2 - 3.f * y2);
    Yv[16] = prm.ycoef[16] * x * y * (x2 - y2);
    Yv[17] = prm.ycoef[17] * y * z * (3.f * x2 - y2);
    Yv[18] = prm.ycoef[18] * x * y * (7.f * z2 - r2);
    Yv[19] = prm.ycoef[19] * y * z * (7.f * z2 - 3.f * r2);
    Yv[20] = prm.ycoef[20] * (35.f * z2 * z2 - 30.f * z2 * r2 + 3.f * r2 * r2);
    Yv[21] = prm.ycoef[21] * x * z * (7.f * z2 - 3.f * r2);
    Yv[22] = prm.ycoef[22] * (x2 - y2) * (7.f * z2 - r2);
    Yv[23] = prm.ycoef[23] * x * z * (x2 - 3.f * y2);
    Yv[24] = prm.ycoef[24] * (x2 * x2 - 6.f * x2 * y2 + y2 * y2);

    // permuted: quad[2+k] = {Y[k], Y[k+8], Y[k+16], Y[k+24]|0}
    float4* q = (float4*)row;
    q[0] = make_float4(g[0], g[1], g[2], g[3]);
    q[1] = make_float4(g[4], g[5], g[6], g[7]);
    q[2] = make_float4(Yv[0], Yv[8],  Yv[16], Yv[24]);
    q[3] = make_float4(Yv[1], Yv[9],  Yv[17], 0.f);
    q[4] = make_float4(Yv[2], Yv[10], Yv[18], 0.f);
    q[5] = make_float4(Yv[3], Yv[11], Yv[19], 0.f);
    q[6] = make_float4(Yv[4], Yv[12], Yv[20], 0.f);
    q[7] = make_float4(Yv[5], Yv[13], Yv[21], 0.f);
    q[8] = make_float4(Yv[6], Yv[14], Yv[22], 0.f);
    q[9] = make_float4(Yv[7], Yv[15], Yv[23], 0.f);
}

__global__ __launch_bounds__(64, 2)
void soap_kernel(const float* __restrict__ pos, const int* __restrict__ Z,
                 float* __restrict__ out, Params prm) {
    // ONE WAVE PER SITE, zero barriers. ILP-batched B phase, padded buckets.
    __shared__ float4 dA[64];                    // A1-compacted (dx,dy,dz,sp)
    __shared__ float4 dB[SLABROWS];              // species-bucketed (padded)
    __shared__ __align__(16) float slab[SLABROWS * ROWW];
    __shared__ __align__(16) float c2[3 * CSLICE];
    __shared__ int spl[64];                      // fallback only

    const int lane = threadIdx.x;
    const int site = blockIdx.x;
    const int jbase = (site >> 9) << 9;
    const unsigned long long ltm = (1ull << lane) - 1ull;

    const float xi = pos[site * 3 + 0];
    const float yi = pos[site * 3 + 1];
    const float zi = pos[site * 3 + 2];

    // ---- A1: scan 512 candidates; species folded in (Z load is parallel) ----
    int mtot = 0;
#pragma unroll
    for (int it = 0; it < 8; ++it) {
        const int ja = jbase + it * 64 + lane;
        const float dx = xi - pos[ja * 3 + 0];
        const float dy = yi - pos[ja * 3 + 1];
        const float dz = zi - pos[ja * 3 + 2];
        const int zz = Z[ja];
        const float d2 = dx * dx + dy * dy + dz * dz;
        const int sp = (zz == 1) ? 0 : (zz == 6) ? 1 : 2;
        const bool pr = d2 < 25.0f;
        const unsigned long long mk = __ballot(pr);
        if (pr) {
            const int sl = mtot + __popcll(mk & ltm);
            if (sl < 64) dA[sl] = make_float4(dx, dy, dz, __int_as_float(sp));
        }
        mtot += __popcll(mk);
    }
    const int M = mtot;

    // ---- zero slab (760 quads) + c2 (216 quads); overlaps A1 load latency ----
    {
        float4* sq = (float4*)slab;
        const float4 z4 = make_float4(0.f, 0.f, 0.f, 0.f);
#pragma unroll
        for (int it = 0; it < 12; ++it) {
            const int i = it * 64 + lane;
            if (i < SLABROWS * 10) sq[i] = z4;
        }
        float4* cq = (float4*)c2;
#pragma unroll
        for (int it = 0; it < 4; ++it) {
            const int i = it * 64 + lane;
            if (i < 216) cq[i] = z4;
        }
    }

    const int n_own = lane & 7;
    const int mrow  = lane >> 3;
    float a0[4] = {0.f,0.f,0.f,0.f};
    float a1[4] = {0.f,0.f,0.f,0.f};
    float a2[4] = {0.f,0.f,0.f,0.f};

    if (M <= 64) {
        // ---- bucket by species into 4-aligned ranges ----
        float4 v = make_float4(0.f, 0.f, 0.f, 0.f);
        int sp = -1;
        if (lane < M) { v = dA[lane]; sp = __float_as_int(v.w); }
        const unsigned long long bb0 = __ballot(sp == 0);
        const unsigned long long bb1 = __ballot(sp == 1);
        const unsigned long long bb2 = __ballot(sp == 2);
        const int n0 = __popcll(bb0), n1 = __popcll(bb1), n2 = __popcll(bb2);
        const int n0p = (n0 + 3) & ~3, n1p = (n1 + 3) & ~3, n2p = (n2 + 3) & ~3;
        const int base1 = n0p, base2 = n0p + n1p, Mp = base2 + n2p;
        int np = -1;
        if (sp == 0)      np = __popcll(bb0 & ltm);
        else if (sp == 1) np = base1 + __popcll(bb1 & ltm);
        else if (sp == 2) np = base2 + __popcll(bb2 & ltm);
        if (np >= 0) dB[np] = v;        // in-wave DS order: read-before-write ok

        // ---- heavy: compute real rows (pad rows stay zero) ----
        for (int rb = 0; rb < Mp; rb += 64) {
            const int row = rb + lane;
            bool real;
            if (row < base1)      real = row < n0;
            else if (row < base2) real = (row - base1) < n1;
            else                  real = (row - base2) < n2;
            if (real && row < Mp) {
                const float4 u = dB[row];
                neighbor_compute(prm, u.x, u.y, u.z, &slab[row * ROWW]);
            }
        }

        // ---- B: 4-slot groups, 8 LDS loads batched before 16 FMAs ----
#define BGROUP(ACC, RSTART, REND)                                              \
        for (int r = (RSTART); r < (REND); r += 4) {                           \
            const float* rp = &slab[r * ROWW];                                 \
            const float g0 = rp[n_own];                                        \
            const float g1 = rp[ROWW + n_own];                                 \
            const float g2 = rp[2 * ROWW + n_own];                             \
            const float g3 = rp[3 * ROWW + n_own];                             \
            const float* yp = rp + 8 + 4 * mrow;                               \
            const float4 y0 = *(const float4*)(yp);                            \
            const float4 y1 = *(const float4*)(yp + ROWW);                     \
            const float4 y2 = *(const float4*)(yp + 2 * ROWW);                 \
            const float4 y3 = *(const float4*)(yp + 3 * ROWW);                 \
            ACC[0] += g0 * y0.x; ACC[1] += g0 * y0.y;                          \
            ACC[2] += g0 * y0.z; ACC[3] += g0 * y0.w;                          \
            ACC[0] += g1 * y1.x; ACC[1] += g1 * y1.y;                          \
            ACC[2] += g1 * y1.z; ACC[3] += g1 * y1.w;                          \
            ACC[0] += g2 * y2.x; ACC[1] += g2 * y2.y;                          \
            ACC[2] += g2 * y2.z; ACC[3] += g2 * y2.w;                          \
            ACC[0] += g3 * y3.x; ACC[1] += g3 * y3.y;                          \
            ACC[2] += g3 * y3.z; ACC[3] += g3 * y3.w;                          \
        }
        BGROUP(a0, 0,     n0p)
        BGROUP(a1, base1, base1 + n1p)
        BGROUP(a2, base2, base2 + n2p)
#undef BGROUP
    } else {
        // ---- fallback (M > 64, practically unreachable): chunked slabs ----
        for (int it = 0; it < 8; ++it) {
            const int ja = jbase + it * 64 + lane;
            const float dx = xi - pos[ja * 3 + 0];
            const float dy = yi - pos[ja * 3 + 1];
            const float dz = zi - pos[ja * 3 + 2];
            const float d2 = dx * dx + dy * dy + dz * dz;
            const bool pr = d2 < 25.0f;
            const unsigned long long mk = __ballot(pr);
            const int cnt = __popcll(mk);
            if (pr) {
                const int sl = __popcll(mk & ltm);
                dA[sl] = make_float4(dx, dy, dz, 0.f);
                const int zz = Z[ja];
                spl[sl] = (zz == 1) ? 0 : (zz == 6) ? 1 : 2;
            }
            if (lane < cnt) {
                const float4 u = dA[lane];
                neighbor_compute(prm, u.x, u.y, u.z, &slab[lane * ROWW]);
            }
            const float* yb = &slab[8 + 4 * mrow];
            for (int sl = 0; sl < cnt; ++sl) {
                const int ss = spl[sl];          // wave-uniform
                const float g = slab[sl * ROWW + n_own];
                const float4 y4 = *(const float4*)&yb[sl * ROWW];
                if (ss == 0) {
                    a0[0] += g * y4.x; a0[1] += g * y4.y; a0[2] += g * y4.z; a0[3] += g * y4.w;
                } else if (ss == 1) {
                    a1[0] += g * y4.x; a1[1] += g * y4.y; a1[2] += g * y4.z; a1[3] += g * y4.w;
                } else {
                    a2[0] += g * y4.x; a2[1] += g * y4.y; a2[2] += g * y4.z; a2[3] += g * y4.w;
                }
            }
        }
    }

    // ---- write c into [s][n][36] packed l-blocks ----
#pragma unroll
    for (int k = 0; k < 4; ++k) {
        const int m = mrow + 8 * k;
        if (k < 3 || mrow == 0) {       // m < 25
            const int l  = (int)sqrtf((float)m);   // exact at perfect squares
            const int kk = m - l * l;
            const int lofs = (l < 2) ? 4 * l : 8 * (l - 1);
            const int idx = n_own * CROW + lofs + kk;
            c2[idx             ] = a0[k];
            c2[idx +     CSLICE] = a1[k];
            c2[idx + 2 * CSLICE] = a2[k];
        }
    }

    // ---- C: 1080 outputs; conflict-free b128 reads, coalesced stores ----
#pragma unroll
    for (int it = 0; it < 17; ++it) {
        const int o = it * 64 + lane;
        if (o < NOUT) {
            const int q   = o / 180;
            const int rem = o - q * 180;
            const int l   = rem / 36;
            const int t   = rem - l * 36;
            const int n = (int)((17.0f - sqrtf((float)(289 - 8 * t))) * 0.5f);
            const int p = t - ((n * (17 - n)) >> 1) + n;
            const int s1 = (q < 3) ? 0 : ((q < 5) ? 1 : 2);
            const int s2 = (q < 3) ? q : ((q < 5) ? (q - 2) : 2);
            const int lofs = (l < 2) ? 4 * l : 8 * (l - 1);
            const int nq   = (l < 2) ? 1 : ((l < 4) ? 2 : 3);
            const float4* ra = (const float4*)&c2[s1 * CSLICE + n * CROW + lofs];
            const float4* rb = (const float4*)&c2[s2 * CSLICE + p * CROW + lofs];
            float sum = 0.f;
            for (int j = 0; j < nq; ++j) {
                const float4 av = ra[j], bv = rb[j];
                sum += av.x * bv.x + av.y * bv.y + av.z * bv.z + av.w * bv.w;
            }
            float sc = prm.pairf[q] * prm.lscale[l];
            if (n != p) sc *= 1.41421356237309515f;
            out[site * NOUT + o] = sum * sc;
        }
    }
}

extern "C" void kernel_launch(void* const* d_in, const int* in_sizes, int n_in,
                              void* d_out, int out_size, void* d_ws, size_t ws_size,
                              hipStream_t stream) {
    const float* pos = (const float*)d_in[0];
    const int*   Z   = (const int*)d_in[1];
    float*       out = (float*)d_out;
    const int nsite  = in_sizes[1];   // B*N = 2048

    Params prm;

    // ---- W_ORTHO = S^(-1/2) via cyclic Jacobi (double precision, host) ----
    double A[8][8], V[8][8];
    for (int i = 0; i < 8; ++i)
        for (int j = 0; j < 8; ++j) {
            const double ai = i + 1.0, aj = j + 1.0;
            A[i][j] = sqrt((5.0 + 2.0 * ai) * (5.0 + 2.0 * aj)) / (5.0 + ai + aj);
            V[i][j] = (i == j) ? 1.0 : 0.0;
        }
    for (int sweep = 0; sweep < 30; ++sweep) {
        for (int p = 0; p < 8; ++p)
            for (int q = p + 1; q < 8; ++q) {
                const double apq = A[p][q];
                if (fabs(apq) < 1e-300) continue;
                const double phi = 0.5 * atan2(2.0 * apq, A[q][q] - A[p][p]);
                const double c = cos(phi), s = sin(phi);
                for (int k = 0; k < 8; ++k) {
                    const double akp = A[k][p], akq = A[k][q];
                    A[k][p] = c * akp - s * akq;
                    A[k][q] = s * akp + c * akq;
                }
                for (int k = 0; k < 8; ++k) {
                    const double apk = A[p][k], aqk = A[q][k];
                    A[p][k] = c * apk - s * aqk;
                    A[q][k] = s * apk + c * aqk;
                }
                for (int k = 0; k < 8; ++k) {
                    const double vkp = V[k][p], vkq = V[k][q];
                    V[k][p] = c * vkp - s * vkq;
                    V[k][q] = s * vkp + c * vkq;
                }
            }
    }
    for (int i = 0; i < 8; ++i)
        for (int j = 0; j < 8; ++j) {
            double acc = 0.0;
            for (int k = 0; k < 8; ++k) acc += V[i][k] * V[j][k] / sqrt(A[k][k]);
            prm.W[i * 8 + j] = (float)acc;
        }

    for (int a = 0; a < 8; ++a)
        prm.invnorm[a] = (float)(1.0 / sqrt(pow(5.0, 2.0 * a + 7.0) / (2.0 * a + 7.0)));

    const double pi = 3.14159265358979323846;
    const double fp = 4.0 * pi;
    double yc[NM];
    yc[0]  = 0.5 * sqrt(1.0 / pi);
    yc[1]  = yc[2] = yc[3] = sqrt(3.0 / (4.0 * pi));
    yc[4]  = yc[5] = yc[7] = 0.5 * sqrt(15.0 / pi);
    yc[6]  = 0.25 * sqrt(5.0 / pi);
    yc[8]  = 0.25 * sqrt(15.0 / pi);
    yc[9]  = yc[15] = 0.25 * sqrt(35.0 / (2.0 * pi));
    yc[10] = 0.5 * sqrt(105.0 / pi);
    yc[11] = yc[13] = 0.25 * sqrt(21.0 / (2.0 * pi));
    yc[12] = 0.25 * sqrt(7.0 / pi);
    yc[14] = 0.25 * sqrt(105.0 / pi);
    yc[16] = 0.75 * sqrt(35.0 / pi);
    yc[17] = yc[23] = 0.75 * sqrt(35.0 / (2.0 * pi));
    yc[18] = 0.75 * sqrt(5.0 / pi);
    yc[19] = yc[21] = 0.75 * sqrt(5.0 / (2.0 * pi));
    yc[20] = 3.0 / 16.0 * sqrt(1.0 / pi);
    yc[22] = 3.0 / 8.0 * sqrt(5.0 / pi);
    yc[24] = 3.0 / 16.0 * sqrt(35.0 / pi);
    for (int m = 0; m < NM; ++m) prm.ycoef[m] = (float)(yc[m] * fp);

    for (int l = 0; l <= 4; ++l) prm.lscale[l] = (float)(pi * sqrt(8.0 / (2.0 * l + 1.0)));
    const float rt2 = 1.41421356237309515f;
    prm.pairf[0] = 1.f; prm.pairf[1] = rt2; prm.pairf[2] = rt2;
    prm.pairf[3] = 1.f; prm.pairf[4] = rt2; prm.pairf[5] = 1.f;

    soap_kernel<<<nsite, 64, 0, stream>>>(pos, Z, out, prm);
}